// Round 7
// baseline (514.471 us; speedup 1.0000x reference)
//
#include <hip/hip_runtime.h>
#include <stdint.h>

typedef unsigned short u16;
typedef _Float16 v8h __attribute__((ext_vector_type(8)));
typedef float v4f __attribute__((ext_vector_type(4)));
typedef float v16f __attribute__((ext_vector_type(16)));

static __device__ __forceinline__ float h2f(u16 u) {
    union { u16 s; _Float16 h; } v; v.s = u; return (float)v.h;
}
static __device__ __forceinline__ u16 f2h(float f) {
    union { u16 s; _Float16 h; } v; v.h = (_Float16)f; return v.s;
}

// async global->LDS, 16B per lane. lds dest = wave-uniform base + lane*16.
static __device__ __forceinline__ void gload_lds16(const u16* g, const u16* l) {
    __builtin_amdgcn_global_load_lds(
        (const __attribute__((address_space(1))) uint32_t*)(uintptr_t)g,
        (__attribute__((address_space(3))) uint32_t*)(uintptr_t)l,
        16, 0, 0);
}

// ---------------- convert f32 -> f16, vectorized x8 ----------------
__global__ __launch_bounds__(256) void cvt_f16(const float* __restrict__ in,
                                               u16* __restrict__ out, int n8) {
    const int i = blockIdx.x * 256 + threadIdx.x;
    if (i >= n8) return;
    const float4 a = ((const float4*)in)[2 * i];
    const float4 b = ((const float4*)in)[2 * i + 1];
    u16 o[8] = {f2h(a.x), f2h(a.y), f2h(a.z), f2h(a.w),
                f2h(b.x), f2h(b.y), f2h(b.z), f2h(b.w)};
    *(uint4*)(out + (size_t)i * 8) = *(const uint4*)o;
}

// ---------------- all weight transposes f32 [R][C] -> f16 [C][R], one launch ----------------
__global__ __launch_bounds__(256) void transpose_all(
    const float* __restrict__ Wq, const float* __restrict__ Wk,
    const float* __restrict__ Wv, const float* __restrict__ Wo,
    const float* __restrict__ W1, const float* __restrict__ W2,
    u16* __restrict__ WqkvT, u16* __restrict__ WoT,
    u16* __restrict__ W1T, u16* __restrict__ W2T)
{
    int t = blockIdx.x;
    const float* in; u16* out; long ldi, ldo; int xt;
    if (t < 1024)      {            in = Wq; out = WqkvT;               ldi = 1024; ldo = 1024; xt = 32; }
    else if (t < 2048) { t -= 1024; in = Wk; out = WqkvT + 1024*1024;   ldi = 1024; ldo = 1024; xt = 32; }
    else if (t < 3072) { t -= 2048; in = Wv; out = WqkvT + 2*1024*1024; ldi = 1024; ldo = 1024; xt = 32; }
    else if (t < 4096) { t -= 3072; in = Wo; out = WoT;                 ldi = 1024; ldo = 1024; xt = 32; }
    else if (t < 8192) { t -= 4096; in = W1; out = W1T;                 ldi = 4096; ldo = 1024; xt = 128; }
    else               { t -= 8192; in = W2; out = W2T;                 ldi = 1024; ldo = 4096; xt = 32; }
    const int c0 = (t % xt) * 32, r0 = (t / xt) * 32;
    __shared__ float tile[32][33];
    for (int i = threadIdx.y; i < 32; i += 8)
        tile[i][threadIdx.x] = in[(long)(r0 + i) * ldi + c0 + threadIdx.x];
    __syncthreads();
    for (int i = threadIdx.y; i < 32; i += 8)
        out[(long)(c0 + i) * ldo + r0 + threadIdx.x] = f2h(tile[threadIdx.x][i]);
}

// ======== 256x128 8-phase f16 GEMM, 4Mx2N wave grid (per-wave 64x64) ========
// r6-proven kernel (16x16x32 MFMA). Used for QKV/scores/PV/Wo/FF2.
template<int OMODE, int BIAS, bool RELU, int NX, int NY, int NZ>
__global__ __launch_bounds__(512, 4) void gemm256n(
    const u16* __restrict__ A, long lda, long Asb,
    const u16* __restrict__ B, long ldb, long Bsb,
    void* __restrict__ Cv, long ldc, long Csb, u16* __restrict__ C1,
    const float* __restrict__ bias, const float* __restrict__ bias2,
    const float* __restrict__ bias3, int K)
{
    constexpr int NWG = NX * NY * NZ;
    static_assert(NWG % 8 == 0, "XCD swizzle needs nwg % 8 == 0");
    alignas(16) __shared__ u16 As[4 * 8192];   // 64 KiB: 4 regions [256][32]
    alignas(16) __shared__ u16 Bs[2 * 4096];   // 16 KiB: 2 slots [128][32]

    const int tid = threadIdx.x;
    const int lane = tid & 63, wave = tid >> 6;
    const int l16 = lane & 15, quad = lane >> 4;
    const int wm = wave >> 1;              // 0..3 (M, 64 rows each)
    const int wn = wave & 1;               // 0..1 (N, 64 cols each)

    const int lin = blockIdx.x;
    const int tl = (lin & 7) * (NWG / 8) + (lin >> 3);
    const int xe = tl % NX;
    const int ye = (tl / NX) % NY;
    const int zb = tl / (NX * NY);
    const long m0 = (long)ye * 256;
    const long n0 = (long)xe * 128;

    const u16* Aop = A + (long)zb * Asb;
    const u16* Bop = B + (long)zb * Bsb;

    const int srow = tid >> 2;                       // 0..127
    const int sq = (tid & 3) ^ ((tid >> 3) & 3);
    const long gaofs0 = (m0 + srow) * lda + sq * 8;
    const long gaofs1 = gaofs0 + 128 * lda;
    const long gbofs0 = (n0 + srow) * ldb + sq * 8;  // B region = 128 rows
    const int wv512n = wave * 512;

    const int swzE = (quad ^ ((l16 >> 1) & 3)) * 8;
    const int aRow = (wm * 64 + l16) * 32 + swzE;
    const int bRow = (wn * 64 + l16) * 32 + swzE;

    v4f acc[4][4];
#pragma unroll
    for (int i = 0; i < 4; ++i)
#pragma unroll
        for (int j = 0; j < 4; ++j)
            acc[i][j] = (v4f){0.f, 0.f, 0.f, 0.f};
    v8h bf[4];

#define STAGE_A(RIDX, KP) do { \
        u16* lb_ = As + (RIDX) * 8192 + wv512n; \
        gload_lds16(Aop + gaofs0 + (KP), lb_); \
        gload_lds16(Aop + gaofs1 + (KP), lb_ + 4096); } while (0)
#define STAGE_B(SLOT, KP) do { \
        gload_lds16(Bop + gbofs0 + (KP), Bs + (SLOT) * 4096 + wv512n); } while (0)

#define PHASE(BUF, KH, CH, EVENW, STG) { \
        if (EVENW) asm volatile("s_waitcnt vmcnt(2)" ::: "memory"); \
        const u16* Ar_ = As + ((BUF) * 2 + (KH)) * 8192 + aRow + (CH) * 1024; \
        v8h af0 = *(const v8h*)(Ar_); \
        v8h af1 = *(const v8h*)(Ar_ + 512); \
        if ((CH) == 0) { \
            const u16* Br_ = Bs + (KH) * 4096 + bRow; \
            bf[0] = *(const v8h*)(Br_); \
            bf[1] = *(const v8h*)(Br_ + 512); \
            bf[2] = *(const v8h*)(Br_ + 1024); \
            bf[3] = *(const v8h*)(Br_ + 1536); \
        } \
        STG; \
        __builtin_amdgcn_s_barrier(); \
        asm volatile("s_waitcnt lgkmcnt(0)" ::: "memory"); \
        __builtin_amdgcn_s_setprio(1); \
        acc[(CH)*2+0][0] = __builtin_amdgcn_mfma_f32_16x16x32_f16(af0, bf[0], acc[(CH)*2+0][0], 0, 0, 0); \
        acc[(CH)*2+0][1] = __builtin_amdgcn_mfma_f32_16x16x32_f16(af0, bf[1], acc[(CH)*2+0][1], 0, 0, 0); \
        acc[(CH)*2+0][2] = __builtin_amdgcn_mfma_f32_16x16x32_f16(af0, bf[2], acc[(CH)*2+0][2], 0, 0, 0); \
        acc[(CH)*2+0][3] = __builtin_amdgcn_mfma_f32_16x16x32_f16(af0, bf[3], acc[(CH)*2+0][3], 0, 0, 0); \
        acc[(CH)*2+1][0] = __builtin_amdgcn_mfma_f32_16x16x32_f16(af1, bf[0], acc[(CH)*2+1][0], 0, 0, 0); \
        acc[(CH)*2+1][1] = __builtin_amdgcn_mfma_f32_16x16x32_f16(af1, bf[1], acc[(CH)*2+1][1], 0, 0, 0); \
        acc[(CH)*2+1][2] = __builtin_amdgcn_mfma_f32_16x16x32_f16(af1, bf[2], acc[(CH)*2+1][2], 0, 0, 0); \
        acc[(CH)*2+1][3] = __builtin_amdgcn_mfma_f32_16x16x32_f16(af1, bf[3], acc[(CH)*2+1][3], 0, 0, 0); \
        __builtin_amdgcn_s_setprio(0); \
        __builtin_amdgcn_s_barrier(); \
    }

    // prologue: A r0,r1,r2 + B slot0,slot1 (8 loads); vmcnt(5) leaves A1,B1,A2
    STAGE_A(0, 0);  STAGE_B(0, 0);
    STAGE_A(1, 32); STAGE_B(1, 32);
    STAGE_A(2, 64);
    asm volatile("s_waitcnt vmcnt(5)" ::: "memory");
    __builtin_amdgcn_s_barrier();

    const int NT = K >> 7;   // K % 128 == 0
#pragma unroll 1
    for (int t = 0; t < NT; ++t) {
        const long kb = (long)t * 128;
        long kp2  = kb + 128; if (kp2  >= K) kp2  = 0;
        long kp2b = kb + 160; if (kp2b >= K) kp2b = 0;
        long kp3  = kb + 192; if (kp3  >= K) kp3  = 0;

        PHASE(0, 0, 0, false, STAGE_A(3, kb + 96))   // P1
        PHASE(0, 0, 1, true,  STAGE_B(0, kb + 64))   // P2
        PHASE(0, 1, 0, false, STAGE_A(0, kp2))       // P3
        PHASE(0, 1, 1, true,  STAGE_B(1, kb + 96))   // P4
        PHASE(1, 0, 0, false, STAGE_A(1, kp2b))      // P5
        PHASE(1, 0, 1, true,  STAGE_B(0, kp2))       // P6
        PHASE(1, 1, 0, false, STAGE_A(2, kp3))       // P7
        PHASE(1, 1, 1, true,  STAGE_B(1, kp2b))      // P8
    }

    // hardened: drain all outstanding DMA/LDS ops before epilogue/endpgm
    asm volatile("s_waitcnt vmcnt(0) lgkmcnt(0)" ::: "memory");
    __builtin_amdgcn_s_barrier();

#undef PHASE
#undef STAGE_A
#undef STAGE_B

    float bv[4];
#pragma unroll
    for (int j = 0; j < 4; ++j) {
        const long col = n0 + wn * 64 + j * 16 + l16;
        if (BIAS == 0) bv[j] = 0.f;
        else if (BIAS == 1) bv[j] = bias[col];
        else {
            const int sel = (int)(col >> 10);
            const float* bp = sel == 0 ? bias : (sel == 1 ? bias2 : bias3);
            bv[j] = bp[col & 1023];
        }
    }

    if (OMODE == 3 && n0 >= 2048) {
        const long bb = m0 >> 11, mb = m0 & 2047;
        u16* C = C1 + bb * Csb;
#pragma unroll
        for (int j = 0; j < 4; ++j) {
            const long col = n0 - 2048 + wn * 64 + j * 16 + l16;
            u16* pc = C + col * 2048 + mb + wm * 64 + quad * 4;
#pragma unroll
            for (int i = 0; i < 4; ++i) {
                u16 o[4];
#pragma unroll
                for (int r = 0; r < 4; ++r) {
                    float val = acc[i][j][r] + bv[j];
                    if (RELU) val = fmaxf(val, 0.f);
                    o[r] = f2h(val);
                }
                *(uint2*)(pc + i * 16) = *(const uint2*)o;
            }
        }
    } else {
        const long cb = (OMODE == 3 ? 0 : (long)zb * Csb)
                      + (m0 + wm * 64 + quad * 4) * ldc + (n0 + wn * 64 + l16);
        u16* p0 = (u16*)Cv + cb;
#pragma unroll
        for (int i = 0; i < 4; ++i)
#pragma unroll
            for (int r = 0; r < 4; ++r) {
                u16* prow = p0 + (long)(i * 16 + r) * ldc;
#pragma unroll
                for (int j = 0; j < 4; ++j) {
                    float val = acc[i][j][r] + bv[j];
                    if (RELU) val = fmaxf(val, 0.f);
                    prow[j * 16] = f2h(val);
                }
            }
    }
}

// ======== gemm32: same skeleton, MFMA 32x32x16 (A/B probe, FF1 only) ========
// Identical staging/sync/swizzle/grid to gemm256n. Per phase: 2 A-frag +
// (CH==0: 4 B-frag) ds_reads, then 4 x mfma_f32_32x32x16_f16 (same FLOP,
// half the MFMA instructions, same ascending-k accumulation).
// Fragment layout (symmetric to verified 16x16 pattern): A/B lane holds
// row/col = lane&31, k = (lane>>5)*8 + idx. Swizzled slot for octet q of
// row r: q ^ ((r>>1)&3) (matches staging permutation, conflict-balanced).
// C/D: col = lane&31, row = (reg&3) + 8*(reg>>2) + 4*(lane>>5)  [m74/m101].
template<int BIAS, bool RELU, int NX, int NY, int NZ>
__global__ __launch_bounds__(512, 4) void gemm32(
    const u16* __restrict__ A, long lda,
    const u16* __restrict__ B, long ldb,
    u16* __restrict__ C, long ldc,
    const float* __restrict__ bias, int K)
{
    constexpr int NWG = NX * NY * NZ;
    static_assert(NWG % 8 == 0, "XCD swizzle needs nwg % 8 == 0");
    alignas(16) __shared__ u16 As[4 * 8192];   // 64 KiB: 4 regions [256][32]
    alignas(16) __shared__ u16 Bs[2 * 4096];   // 16 KiB: 2 slots [128][32]

    const int tid = threadIdx.x;
    const int lane = tid & 63, wave = tid >> 6;
    const int l32 = lane & 31, koct = lane >> 5;   // 0..1
    const int wm = wave >> 1;              // 0..3 (M, 64 rows each)
    const int wn = wave & 1;               // 0..1 (N, 64 cols each)

    const int lin = blockIdx.x;
    const int tl = (lin & 7) * (NWG / 8) + (lin >> 3);
    const int xe = tl % NX;
    const int ye = (tl / NX) % NY;
    const long m0 = (long)ye * 256;
    const long n0 = (long)xe * 128;

    const int srow = tid >> 2;
    const int sq = (tid & 3) ^ ((tid >> 3) & 3);
    const long gaofs0 = (m0 + srow) * lda + sq * 8;
    const long gaofs1 = gaofs0 + 128 * lda;
    const long gbofs0 = (n0 + srow) * ldb + sq * 8;
    const int wv512n = wave * 512;

    // fragment addressing: row/col = base + l32; octet for k-slice s = s*2+koct
    const int amask = (l32 >> 1) & 3;
    const int s0 = (koct ^ amask) * 8;             // k 0..15  (octets 0,1)
    const int s1 = ((2 + koct) ^ amask) * 8;       // k 16..31 (octets 2,3)
    const int aBase = (wm * 64 + l32) * 32;        // + CH*1024 per phase
    const int bBase = (wn * 64 + l32) * 32;        // + cb*1024

    v16f acc[2][2];
#pragma unroll
    for (int i = 0; i < 2; ++i)
#pragma unroll
        for (int j = 0; j < 2; ++j)
#pragma unroll
            for (int r = 0; r < 16; ++r) acc[i][j][r] = 0.f;
    v8h bf00, bf01, bf10, bf11;

#define STAGE_A(RIDX, KP) do { \
        u16* lb_ = As + (RIDX) * 8192 + wv512n; \
        gload_lds16(A + gaofs0 + (KP), lb_); \
        gload_lds16(A + gaofs1 + (KP), lb_ + 4096); } while (0)
#define STAGE_B(SLOT, KP) do { \
        gload_lds16(B + gbofs0 + (KP), Bs + (SLOT) * 4096 + wv512n); } while (0)

#define PHASE(BUF, KH, CH, EVENW, STG) { \
        if (EVENW) asm volatile("s_waitcnt vmcnt(2)" ::: "memory"); \
        const u16* Ar_ = As + ((BUF) * 2 + (KH)) * 8192 + aBase + (CH) * 1024; \
        v8h af0 = *(const v8h*)(Ar_ + s0); \
        v8h af1 = *(const v8h*)(Ar_ + s1); \
        if ((CH) == 0) { \
            const u16* Br_ = Bs + (KH) * 4096 + bBase; \
            bf00 = *(const v8h*)(Br_ + s0); \
            bf01 = *(const v8h*)(Br_ + s1); \
            bf10 = *(const v8h*)(Br_ + 1024 + s0); \
            bf11 = *(const v8h*)(Br_ + 1024 + s1); \
        } \
        STG; \
        __builtin_amdgcn_s_barrier(); \
        asm volatile("s_waitcnt lgkmcnt(0)" ::: "memory"); \
        __builtin_amdgcn_s_setprio(1); \
        acc[CH][0] = __builtin_amdgcn_mfma_f32_32x32x16_f16(af0, bf00, acc[CH][0], 0, 0, 0); \
        acc[CH][1] = __builtin_amdgcn_mfma_f32_32x32x16_f16(af0, bf10, acc[CH][1], 0, 0, 0); \
        acc[CH][0] = __builtin_amdgcn_mfma_f32_32x32x16_f16(af1, bf01, acc[CH][0], 0, 0, 0); \
        acc[CH][1] = __builtin_amdgcn_mfma_f32_32x32x16_f16(af1, bf11, acc[CH][1], 0, 0, 0); \
        __builtin_amdgcn_s_setprio(0); \
        __builtin_amdgcn_s_barrier(); \
    }

    // prologue: identical to gemm256n
    STAGE_A(0, 0);  STAGE_B(0, 0);
    STAGE_A(1, 32); STAGE_B(1, 32);
    STAGE_A(2, 64);
    asm volatile("s_waitcnt vmcnt(5)" ::: "memory");
    __builtin_amdgcn_s_barrier();

    const int NT = K >> 7;   // K % 128 == 0
#pragma unroll 1
    for (int t = 0; t < NT; ++t) {
        const long kb = (long)t * 128;
        long kp2  = kb + 128; if (kp2  >= K) kp2  = 0;
        long kp2b = kb + 160; if (kp2b >= K) kp2b = 0;
        long kp3  = kb + 192; if (kp3  >= K) kp3  = 0;

        PHASE(0, 0, 0, false, STAGE_A(3, kb + 96))   // P1
        PHASE(0, 0, 1, true,  STAGE_B(0, kb + 64))   // P2
        PHASE(0, 1, 0, false, STAGE_A(0, kp2))       // P3
        PHASE(0, 1, 1, true,  STAGE_B(1, kb + 96))   // P4
        PHASE(1, 0, 0, false, STAGE_A(1, kp2b))      // P5
        PHASE(1, 0, 1, true,  STAGE_B(0, kp2))       // P6
        PHASE(1, 1, 0, false, STAGE_A(2, kp3))       // P7
        PHASE(1, 1, 1, true,  STAGE_B(1, kp2b))      // P8
    }

    asm volatile("s_waitcnt vmcnt(0) lgkmcnt(0)" ::: "memory");
    __builtin_amdgcn_s_barrier();

#undef PHASE
#undef STAGE_A
#undef STAGE_B

    float bv[2];
#pragma unroll
    for (int j = 0; j < 2; ++j) {
        const long col = n0 + wn * 64 + j * 32 + l32;
        bv[j] = (BIAS == 1) ? bias[col] : 0.f;
    }

    // C/D: col = lane&31, row = (reg&3) + 8*(reg>>2) + 4*koct
#pragma unroll
    for (int rb = 0; rb < 2; ++rb)
#pragma unroll
        for (int cb = 0; cb < 2; ++cb) {
            const long col = n0 + wn * 64 + cb * 32 + l32;
            u16* pc = C + (m0 + wm * 64 + rb * 32 + 4 * koct) * ldc + col;
#pragma unroll
            for (int reg = 0; reg < 16; ++reg) {
                const long row = (reg & 3) + 8 * (reg >> 2);
                float val = acc[rb][cb][reg] + bv[cb];
                if (RELU) val = fmaxf(val, 0.f);
                pc[row * ldc] = f2h(val);
            }
        }
}

// ---------------- softmax over f16 rows of 2048, in place ----------------
__global__ __launch_bounds__(256) void softmax_rows(u16* __restrict__ S) {
    const long row = blockIdx.x;
    u16* p = S + row * 2048;
    const int t = threadIdx.x;
    float v[8];
    float mx = -1e30f;
#pragma unroll
    for (int i = 0; i < 8; ++i) { v[i] = h2f(p[t + i * 256]); mx = fmaxf(mx, v[i]); }
    __shared__ float red[256];
    red[t] = mx; __syncthreads();
    for (int off = 128; off > 0; off >>= 1) {
        if (t < off) red[t] = fmaxf(red[t], red[t + off]);
        __syncthreads();
    }
    mx = red[0]; __syncthreads();
    float sum = 0.f;
#pragma unroll
    for (int i = 0; i < 8; ++i) { v[i] = __expf(v[i] - mx); sum += v[i]; }
    red[t] = sum; __syncthreads();
    for (int off = 128; off > 0; off >>= 1) {
        if (t < off) red[t] += red[t + off];
        __syncthreads();
    }
    const float inv = 1.f / red[0];
#pragma unroll
    for (int i = 0; i < 8; ++i) p[t + i * 256] = f2h(v[i] * inv);
}

// ---------------- ln1: xh_f16 = LN(src_f32 + attnO_f16) ----------------
__global__ __launch_bounds__(256) void ln_one(
    const float* __restrict__ a, const u16* __restrict__ bb,
    const float* __restrict__ g, const float* __restrict__ be,
    u16* __restrict__ out16)
{
    const long base = (long)blockIdx.x * 1024;
    const int t = threadIdx.x;
    float v[4]; float s = 0.f, ss = 0.f;
#pragma unroll
    for (int i = 0; i < 4; ++i) {
        const int c = t + i * 256;
        const float x = a[base + c] + h2f(bb[base + c]);
        v[i] = x; s += x; ss += x * x;
    }
    __shared__ float rs[256], rss[256];
    rs[t] = s; rss[t] = ss; __syncthreads();
    for (int off = 128; off > 0; off >>= 1) {
        if (t < off) { rs[t] += rs[t + off]; rss[t] += rss[t + off]; }
        __syncthreads();
    }
    const float mean = rs[0] * (1.f / 1024.f);
    const float var = rss[0] * (1.f / 1024.f) - mean * mean;
    const float rstd = rsqrtf(var + 1e-5f);
#pragma unroll
    for (int i = 0; i < 4; ++i) {
        const int c = t + i * 256;
        out16[base + c] = f2h((v[i] - mean) * rstd * g[c] + be[c]);
    }
}

// ---------------- ln2: out_f32 = LN(xh_f16 + ffO_f16) ----------------
__global__ __launch_bounds__(256) void ln_two(
    const u16* __restrict__ a, const u16* __restrict__ bb,
    const float* __restrict__ g, const float* __restrict__ be,
    float* __restrict__ out)
{
    const long base = (long)blockIdx.x * 1024;
    const int t = threadIdx.x;
    float v[4]; float s = 0.f, ss = 0.f;
#pragma unroll
    for (int i = 0; i < 4; ++i) {
        const int c = t + i * 256;
        const float x = h2f(a[base + c]) + h2f(bb[base + c]);
        v[i] = x; s += x; ss += x * x;
    }
    __shared__ float rs[256], rss[256];
    rs[t] = s; rss[t] = ss; __syncthreads();
    for (int off = 128; off > 0; off >>= 1) {
        if (t < off) { rs[t] += rs[t + off]; rss[t] += rss[t + off]; }
        __syncthreads();
    }
    const float mean = rs[0] * (1.f / 1024.f);
    const float var = rss[0] * (1.f / 1024.f) - mean * mean;
    const float rstd = rsqrtf(var + 1e-5f);
#pragma unroll
    for (int i = 0; i < 4; ++i) {
        const int c = t + i * 256;
        out[base + c] = (v[i] - mean) * rstd * g[c] + be[c];
    }
}

extern "C" void kernel_launch(void* const* d_in, const int* in_sizes, int n_in,
                              void* d_out, int out_size, void* d_ws, size_t ws_size,
                              hipStream_t stream) {
    (void)in_sizes; (void)n_in; (void)out_size; (void)ws_size;
    constexpr long S = 2048, E = 1024, F = 4096, M = 8192;

    const float* src = (const float*)d_in[0];
    const float* Wq  = (const float*)d_in[1];
    const float* bq  = (const float*)d_in[2];
    const float* Wk  = (const float*)d_in[3];
    const float* bk  = (const float*)d_in[4];
    const float* Wv  = (const float*)d_in[5];
    const float* bv  = (const float*)d_in[6];
    const float* Wo  = (const float*)d_in[7];
    const float* bo  = (const float*)d_in[8];
    const float* W1  = (const float*)d_in[9];
    const float* b1  = (const float*)d_in[10];
    const float* W2  = (const float*)d_in[11];
    const float* b2  = (const float*)d_in[12];
    const float* g1  = (const float*)d_in[13];
    const float* be1 = (const float*)d_in[14];
    const float* g2  = (const float*)d_in[15];
    const float* be2 = (const float*)d_in[16];

    char* ws = (char*)d_ws;
    size_t off = 0;
    auto take = [&](size_t bytes) {
        char* p = ws + off;
        off += (bytes + 255) & ~(size_t)255;
        return p;
    };
    const size_t MB16 = 16777216;  // f16 [8192][1024]
    u16*   srcH  = (u16*)take(MB16);
    u16*   WqkvT = (u16*)take(3 * E * E * 2);     // [3072][1024]: WqT | WkT | WvT
    u16*   WoT   = (u16*)take(E * E * 2);
    u16*   W1T   = (u16*)take(F * E * 2);         // [4096][1024]
    u16*   W2T   = (u16*)take(E * F * 2);         // [1024][4096]
    char*  B0    = take(2 * MB16);                // QK f16 [8192][2048]
    char*  B1    = take(MB16);                    // VT f16 [4][1024][2048]
    char*  B2    = take(4ull * S * S * 4);        // Sh f16 (32M) -> hf f16 [8192][4096] (64M)
    char*  B3    = take(MB16);                    // attn f16 -> xh f16
    char*  B4    = take(MB16);                    // attnO f16 -> ffO f16

    u16*   QK    = (u16*)B0;
    u16*   VT    = (u16*)B1;
    u16*   Sh    = (u16*)B2;
    u16*   hf    = (u16*)B2;
    u16*   attn  = (u16*)B3;
    u16*   xh    = (u16*)B3;
    u16*   attnO = (u16*)B4;
    u16*   ffO   = (u16*)B4;

    dim3 blk(256), blk5(512), tb(32, 8);

    // 1) convert src -> f16
    cvt_f16<<<dim3(M * E / 8 / 256), blk, 0, stream>>>(src, srcH, M * E / 8);

    // 2) all weight transposes in one launch
    transpose_all<<<dim3(12288), tb, 0, stream>>>(Wq, Wk, Wv, Wo, W1, W2,
                                                  WqkvT, WoT, W1T, W2T);

    // 3) merged Q|K|V projection: 768 blocks
    gemm256n<3, 3, false, 24, 32, 1><<<dim3(24 * 32), blk5, 0, stream>>>(
        srcH, E, 0, WqkvT, E, 0, QK, 2 * E, E * S, VT, bq, bk, bv, E);

    // 4) scores[b] = Q[b] @ K[b]^T: 512 blocks
    gemm256n<0, 0, false, 16, 8, 4><<<dim3(16 * 8 * 4), blk5, 0, stream>>>(
        QK, 2 * E, S * 2 * E, QK + E, 2 * E, S * 2 * E,
        Sh, S, S * S, nullptr, nullptr, nullptr, nullptr, E);

    // 5) softmax in place (f16)
    softmax_rows<<<dim3(M), blk, 0, stream>>>(Sh);

    // 6) attn[b] = P[b] @ V[b]: 256 blocks
    gemm256n<0, 0, false, 8, 8, 4><<<dim3(8 * 8 * 4), blk5, 0, stream>>>(
        Sh, S, S * S, VT, S, E * S,
        attn, E, S * E, nullptr, nullptr, nullptr, nullptr, S);

    // 7) attnO = attn @ Wo + bo: 256 blocks
    gemm256n<0, 1, false, 8, 32, 1><<<dim3(8 * 32), blk5, 0, stream>>>(
        attn, E, 0, WoT, E, 0, attnO, E, 0, nullptr, bo, nullptr, nullptr, E);

    // 8) xh = LN(src + attnO) (f16, over dead attn)
    ln_one<<<dim3(M), blk, 0, stream>>>(src, attnO, g1, be1, xh);

    // 9) hf = relu(xh @ W1 + b1): A/B probe — 32x32x16 MFMA variant, 1024 blocks
    gemm32<1, true, 32, 32, 1><<<dim3(32 * 32), blk5, 0, stream>>>(
        xh, E, W1T, E, hf, F, b1, E);

    // 10) ffO = hf @ W2 + b2: 256 blocks, K=4096
    gemm256n<0, 1, false, 8, 32, 1><<<dim3(8 * 32), blk5, 0, stream>>>(
        hf, F, 0, W2T, F, 0, ffO, E, 0, nullptr, b2, nullptr, nullptr, F);

    // 11) out = LN(xh + ffO) -> f32
    ln_two<<<dim3(M), blk, 0, stream>>>(xh, ffO, g2, be2, (float*)d_out);
}

// Round 8
// 481.473 us; speedup vs baseline: 1.0685x; 1.0685x over previous
//
#include <hip/hip_runtime.h>
#include <stdint.h>

typedef unsigned short u16;
typedef _Float16 v8h __attribute__((ext_vector_type(8)));
typedef float v4f __attribute__((ext_vector_type(4)));

static __device__ __forceinline__ float h2f(u16 u) {
    union { u16 s; _Float16 h; } v; v.s = u; return (float)v.h;
}
static __device__ __forceinline__ u16 f2h(float f) {
    union { u16 s; _Float16 h; } v; v.h = (_Float16)f; return v.s;
}

// async global->LDS, 16B per lane. lds dest = wave-uniform base + lane*16.
static __device__ __forceinline__ void gload_lds16(const u16* g, const u16* l) {
    __builtin_amdgcn_global_load_lds(
        (const __attribute__((address_space(1))) uint32_t*)(uintptr_t)g,
        (__attribute__((address_space(3))) uint32_t*)(uintptr_t)l,
        16, 0, 0);
}

// ---------------- convert f32 -> f16, vectorized x8 ----------------
__global__ __launch_bounds__(256) void cvt_f16(const float* __restrict__ in,
                                               u16* __restrict__ out, int n8) {
    const int i = blockIdx.x * 256 + threadIdx.x;
    if (i >= n8) return;
    const float4 a = ((const float4*)in)[2 * i];
    const float4 b = ((const float4*)in)[2 * i + 1];
    u16 o[8] = {f2h(a.x), f2h(a.y), f2h(a.z), f2h(a.w),
                f2h(b.x), f2h(b.y), f2h(b.z), f2h(b.w)};
    *(uint4*)(out + (size_t)i * 8) = *(const uint4*)o;
}

// ---------------- all weight transposes f32 [R][C] -> f16 [C][R], one launch ----------------
__global__ __launch_bounds__(256) void transpose_all(
    const float* __restrict__ Wq, const float* __restrict__ Wk,
    const float* __restrict__ Wv, const float* __restrict__ Wo,
    const float* __restrict__ W1, const float* __restrict__ W2,
    u16* __restrict__ WqkvT, u16* __restrict__ WoT,
    u16* __restrict__ W1T, u16* __restrict__ W2T)
{
    int t = blockIdx.x;
    const float* in; u16* out; long ldi, ldo; int xt;
    if (t < 1024)      {            in = Wq; out = WqkvT;               ldi = 1024; ldo = 1024; xt = 32; }
    else if (t < 2048) { t -= 1024; in = Wk; out = WqkvT + 1024*1024;   ldi = 1024; ldo = 1024; xt = 32; }
    else if (t < 3072) { t -= 2048; in = Wv; out = WqkvT + 2*1024*1024; ldi = 1024; ldo = 1024; xt = 32; }
    else if (t < 4096) { t -= 3072; in = Wo; out = WoT;                 ldi = 1024; ldo = 1024; xt = 32; }
    else if (t < 8192) { t -= 4096; in = W1; out = W1T;                 ldi = 4096; ldo = 1024; xt = 128; }
    else               { t -= 8192; in = W2; out = W2T;                 ldi = 1024; ldo = 4096; xt = 32; }
    const int c0 = (t % xt) * 32, r0 = (t / xt) * 32;
    __shared__ float tile[32][33];
    for (int i = threadIdx.y; i < 32; i += 8)
        tile[i][threadIdx.x] = in[(long)(r0 + i) * ldi + c0 + threadIdx.x];
    __syncthreads();
    for (int i = threadIdx.y; i < 32; i += 8)
        out[(long)(c0 + i) * ldo + r0 + threadIdx.x] = f2h(tile[threadIdx.x][i]);
}

// ======== 256x128 8-phase f16 GEMM, 4Mx2N wave grid (per-wave 64x64) ========
// r6-proven kernel (16x16x32 MFMA). Used for ALL GEMMs.
template<int OMODE, int BIAS, bool RELU, int NX, int NY, int NZ>
__global__ __launch_bounds__(512, 4) void gemm256n(
    const u16* __restrict__ A, long lda, long Asb,
    const u16* __restrict__ B, long ldb, long Bsb,
    void* __restrict__ Cv, long ldc, long Csb, u16* __restrict__ C1,
    const float* __restrict__ bias, const float* __restrict__ bias2,
    const float* __restrict__ bias3, int K)
{
    constexpr int NWG = NX * NY * NZ;
    static_assert(NWG % 8 == 0, "XCD swizzle needs nwg % 8 == 0");
    alignas(16) __shared__ u16 As[4 * 8192];   // 64 KiB: 4 regions [256][32]
    alignas(16) __shared__ u16 Bs[2 * 4096];   // 16 KiB: 2 slots [128][32]

    const int tid = threadIdx.x;
    const int lane = tid & 63, wave = tid >> 6;
    const int l16 = lane & 15, quad = lane >> 4;
    const int wm = wave >> 1;              // 0..3 (M, 64 rows each)
    const int wn = wave & 1;               // 0..1 (N, 64 cols each)

    const int lin = blockIdx.x;
    const int tl = (lin & 7) * (NWG / 8) + (lin >> 3);
    const int xe = tl % NX;
    const int ye = (tl / NX) % NY;
    const int zb = tl / (NX * NY);
    const long m0 = (long)ye * 256;
    const long n0 = (long)xe * 128;

    const u16* Aop = A + (long)zb * Asb;
    const u16* Bop = B + (long)zb * Bsb;

    const int srow = tid >> 2;                       // 0..127
    const int sq = (tid & 3) ^ ((tid >> 3) & 3);
    const long gaofs0 = (m0 + srow) * lda + sq * 8;
    const long gaofs1 = gaofs0 + 128 * lda;
    const long gbofs0 = (n0 + srow) * ldb + sq * 8;  // B region = 128 rows
    const int wv512n = wave * 512;

    const int swzE = (quad ^ ((l16 >> 1) & 3)) * 8;
    const int aRow = (wm * 64 + l16) * 32 + swzE;
    const int bRow = (wn * 64 + l16) * 32 + swzE;

    v4f acc[4][4];
#pragma unroll
    for (int i = 0; i < 4; ++i)
#pragma unroll
        for (int j = 0; j < 4; ++j)
            acc[i][j] = (v4f){0.f, 0.f, 0.f, 0.f};
    v8h bf[4];

#define STAGE_A(RIDX, KP) do { \
        u16* lb_ = As + (RIDX) * 8192 + wv512n; \
        gload_lds16(Aop + gaofs0 + (KP), lb_); \
        gload_lds16(Aop + gaofs1 + (KP), lb_ + 4096); } while (0)
#define STAGE_B(SLOT, KP) do { \
        gload_lds16(Bop + gbofs0 + (KP), Bs + (SLOT) * 4096 + wv512n); } while (0)

#define PHASE(BUF, KH, CH, EVENW, STG) { \
        if (EVENW) asm volatile("s_waitcnt vmcnt(2)" ::: "memory"); \
        const u16* Ar_ = As + ((BUF) * 2 + (KH)) * 8192 + aRow + (CH) * 1024; \
        v8h af0 = *(const v8h*)(Ar_); \
        v8h af1 = *(const v8h*)(Ar_ + 512); \
        if ((CH) == 0) { \
            const u16* Br_ = Bs + (KH) * 4096 + bRow; \
            bf[0] = *(const v8h*)(Br_); \
            bf[1] = *(const v8h*)(Br_ + 512); \
            bf[2] = *(const v8h*)(Br_ + 1024); \
            bf[3] = *(const v8h*)(Br_ + 1536); \
        } \
        STG; \
        __builtin_amdgcn_s_barrier(); \
        asm volatile("s_waitcnt lgkmcnt(0)" ::: "memory"); \
        __builtin_amdgcn_s_setprio(1); \
        acc[(CH)*2+0][0] = __builtin_amdgcn_mfma_f32_16x16x32_f16(af0, bf[0], acc[(CH)*2+0][0], 0, 0, 0); \
        acc[(CH)*2+0][1] = __builtin_amdgcn_mfma_f32_16x16x32_f16(af0, bf[1], acc[(CH)*2+0][1], 0, 0, 0); \
        acc[(CH)*2+0][2] = __builtin_amdgcn_mfma_f32_16x16x32_f16(af0, bf[2], acc[(CH)*2+0][2], 0, 0, 0); \
        acc[(CH)*2+0][3] = __builtin_amdgcn_mfma_f32_16x16x32_f16(af0, bf[3], acc[(CH)*2+0][3], 0, 0, 0); \
        acc[(CH)*2+1][0] = __builtin_amdgcn_mfma_f32_16x16x32_f16(af1, bf[0], acc[(CH)*2+1][0], 0, 0, 0); \
        acc[(CH)*2+1][1] = __builtin_amdgcn_mfma_f32_16x16x32_f16(af1, bf[1], acc[(CH)*2+1][1], 0, 0, 0); \
        acc[(CH)*2+1][2] = __builtin_amdgcn_mfma_f32_16x16x32_f16(af1, bf[2], acc[(CH)*2+1][2], 0, 0, 0); \
        acc[(CH)*2+1][3] = __builtin_amdgcn_mfma_f32_16x16x32_f16(af1, bf[3], acc[(CH)*2+1][3], 0, 0, 0); \
        __builtin_amdgcn_s_setprio(0); \
        __builtin_amdgcn_s_barrier(); \
    }

    // prologue: A r0,r1,r2 + B slot0,slot1 (8 loads); vmcnt(5) leaves A1,B1,A2
    STAGE_A(0, 0);  STAGE_B(0, 0);
    STAGE_A(1, 32); STAGE_B(1, 32);
    STAGE_A(2, 64);
    asm volatile("s_waitcnt vmcnt(5)" ::: "memory");
    __builtin_amdgcn_s_barrier();

    const int NT = K >> 7;   // K % 128 == 0
#pragma unroll 1
    for (int t = 0; t < NT; ++t) {
        const long kb = (long)t * 128;
        long kp2  = kb + 128; if (kp2  >= K) kp2  = 0;
        long kp2b = kb + 160; if (kp2b >= K) kp2b = 0;
        long kp3  = kb + 192; if (kp3  >= K) kp3  = 0;

        PHASE(0, 0, 0, false, STAGE_A(3, kb + 96))   // P1
        PHASE(0, 0, 1, true,  STAGE_B(0, kb + 64))   // P2
        PHASE(0, 1, 0, false, STAGE_A(0, kp2))       // P3
        PHASE(0, 1, 1, true,  STAGE_B(1, kb + 96))   // P4
        PHASE(1, 0, 0, false, STAGE_A(1, kp2b))      // P5
        PHASE(1, 0, 1, true,  STAGE_B(0, kp2))       // P6
        PHASE(1, 1, 0, false, STAGE_A(2, kp3))       // P7
        PHASE(1, 1, 1, true,  STAGE_B(1, kp2b))      // P8
    }

    // hardened: drain all outstanding DMA/LDS ops before epilogue/endpgm
    asm volatile("s_waitcnt vmcnt(0) lgkmcnt(0)" ::: "memory");
    __builtin_amdgcn_s_barrier();

#undef PHASE
#undef STAGE_A
#undef STAGE_B

    float bv[4];
#pragma unroll
    for (int j = 0; j < 4; ++j) {
        const long col = n0 + wn * 64 + j * 16 + l16;
        if (BIAS == 0) bv[j] = 0.f;
        else if (BIAS == 1) bv[j] = bias[col];
        else {
            const int sel = (int)(col >> 10);
            const float* bp = sel == 0 ? bias : (sel == 1 ? bias2 : bias3);
            bv[j] = bp[col & 1023];
        }
    }

    if (OMODE == 3 && n0 >= 2048) {
        const long bb = m0 >> 11, mb = m0 & 2047;
        u16* C = C1 + bb * Csb;
#pragma unroll
        for (int j = 0; j < 4; ++j) {
            const long col = n0 - 2048 + wn * 64 + j * 16 + l16;
            u16* pc = C + col * 2048 + mb + wm * 64 + quad * 4;
#pragma unroll
            for (int i = 0; i < 4; ++i) {
                u16 o[4];
#pragma unroll
                for (int r = 0; r < 4; ++r) {
                    float val = acc[i][j][r] + bv[j];
                    if (RELU) val = fmaxf(val, 0.f);
                    o[r] = f2h(val);
                }
                *(uint2*)(pc + i * 16) = *(const uint2*)o;
            }
        }
    } else {
        const long cb = (OMODE == 3 ? 0 : (long)zb * Csb)
                      + (m0 + wm * 64 + quad * 4) * ldc + (n0 + wn * 64 + l16);
        u16* p0 = (u16*)Cv + cb;
#pragma unroll
        for (int i = 0; i < 4; ++i)
#pragma unroll
            for (int r = 0; r < 4; ++r) {
                u16* prow = p0 + (long)(i * 16 + r) * ldc;
#pragma unroll
                for (int j = 0; j < 4; ++j) {
                    float val = acc[i][j][r] + bv[j];
                    if (RELU) val = fmaxf(val, 0.f);
                    prow[j * 16] = f2h(val);
                }
            }
    }
}

// ---------------- softmax over f16 rows of 2048, in place ----------------
// Vectorized (uint4 = 8 f16 contiguous per thread) + wave shuffle reduce.
__global__ __launch_bounds__(256) void softmax_rows(u16* __restrict__ S) {
    const long row = blockIdx.x;
    u16* p = S + row * 2048;
    const int t = threadIdx.x;
    const int lane = t & 63, wv = t >> 6;

    union { uint4 u; u16 h[8]; } ld;
    ld.u = *(const uint4*)(p + t * 8);
    float v[8];
    float mx = -1e30f;
#pragma unroll
    for (int i = 0; i < 8; ++i) { v[i] = h2f(ld.h[i]); mx = fmaxf(mx, v[i]); }
#pragma unroll
    for (int o = 1; o < 64; o <<= 1) mx = fmaxf(mx, __shfl_xor(mx, o, 64));
    __shared__ float cw[4], cs[4];
    if (lane == 0) cw[wv] = mx;
    __syncthreads();
    mx = fmaxf(fmaxf(cw[0], cw[1]), fmaxf(cw[2], cw[3]));

    float sum = 0.f;
#pragma unroll
    for (int i = 0; i < 8; ++i) { v[i] = __expf(v[i] - mx); sum += v[i]; }
#pragma unroll
    for (int o = 1; o < 64; o <<= 1) sum += __shfl_xor(sum, o, 64);
    if (lane == 0) cs[wv] = sum;
    __syncthreads();
    sum = (cs[0] + cs[1]) + (cs[2] + cs[3]);

    const float inv = 1.f / sum;
#pragma unroll
    for (int i = 0; i < 8; ++i) ld.h[i] = f2h(v[i] * inv);
    *(uint4*)(p + t * 8) = ld.u;
}

// ---------------- ln1: xh_f16 = LN(src_f32 + attnO_f16) ----------------
// Vectorized (4 contiguous/thread) + wave shuffle reduce.
__global__ __launch_bounds__(256) void ln_one(
    const float* __restrict__ a, const u16* __restrict__ bb,
    const float* __restrict__ g, const float* __restrict__ be,
    u16* __restrict__ out16)
{
    const long base = (long)blockIdx.x * 1024;
    const int t = threadIdx.x;
    const int lane = t & 63, wv = t >> 6;
    const int c0 = t * 4;

    const float4 av = *(const float4*)(a + base + c0);
    union { uint2 u; u16 h[4]; } bv;
    bv.u = *(const uint2*)(bb + base + c0);
    float v[4] = {av.x + h2f(bv.h[0]), av.y + h2f(bv.h[1]),
                  av.z + h2f(bv.h[2]), av.w + h2f(bv.h[3])};
    float s = 0.f, ss = 0.f;
#pragma unroll
    for (int i = 0; i < 4; ++i) { s += v[i]; ss += v[i] * v[i]; }
#pragma unroll
    for (int o = 1; o < 64; o <<= 1) { s += __shfl_xor(s, o, 64); ss += __shfl_xor(ss, o, 64); }
    __shared__ float cs[4], css[4];
    if (lane == 0) { cs[wv] = s; css[wv] = ss; }
    __syncthreads();
    s  = (cs[0] + cs[1]) + (cs[2] + cs[3]);
    ss = (css[0] + css[1]) + (css[2] + css[3]);

    const float mean = s * (1.f / 1024.f);
    const float var = ss * (1.f / 1024.f) - mean * mean;
    const float rstd = rsqrtf(var + 1e-5f);
    const float4 gv = *(const float4*)(g + c0);
    const float4 bev = *(const float4*)(be + c0);
    u16 o[4] = {f2h((v[0] - mean) * rstd * gv.x + bev.x),
                f2h((v[1] - mean) * rstd * gv.y + bev.y),
                f2h((v[2] - mean) * rstd * gv.z + bev.z),
                f2h((v[3] - mean) * rstd * gv.w + bev.w)};
    *(uint2*)(out16 + base + c0) = *(const uint2*)o;
}

// ---------------- ln2: out_f32 = LN(xh_f16 + ffO_f16) ----------------
__global__ __launch_bounds__(256) void ln_two(
    const u16* __restrict__ a, const u16* __restrict__ bb,
    const float* __restrict__ g, const float* __restrict__ be,
    float* __restrict__ out)
{
    const long base = (long)blockIdx.x * 1024;
    const int t = threadIdx.x;
    const int lane = t & 63, wv = t >> 6;
    const int c0 = t * 4;

    union { uint2 u; u16 h[4]; } avu, bvu;
    avu.u = *(const uint2*)(a + base + c0);
    bvu.u = *(const uint2*)(bb + base + c0);
    float v[4];
    float s = 0.f, ss = 0.f;
#pragma unroll
    for (int i = 0; i < 4; ++i) {
        v[i] = h2f(avu.h[i]) + h2f(bvu.h[i]);
        s += v[i]; ss += v[i] * v[i];
    }
#pragma unroll
    for (int o = 1; o < 64; o <<= 1) { s += __shfl_xor(s, o, 64); ss += __shfl_xor(ss, o, 64); }
    __shared__ float cs[4], css[4];
    if (lane == 0) { cs[wv] = s; css[wv] = ss; }
    __syncthreads();
    s  = (cs[0] + cs[1]) + (cs[2] + cs[3]);
    ss = (css[0] + css[1]) + (css[2] + css[3]);

    const float mean = s * (1.f / 1024.f);
    const float var = ss * (1.f / 1024.f) - mean * mean;
    const float rstd = rsqrtf(var + 1e-5f);
    const float4 gv = *(const float4*)(g + c0);
    const float4 bev = *(const float4*)(be + c0);
    float4 o;
    o.x = (v[0] - mean) * rstd * gv.x + bev.x;
    o.y = (v[1] - mean) * rstd * gv.y + bev.y;
    o.z = (v[2] - mean) * rstd * gv.z + bev.z;
    o.w = (v[3] - mean) * rstd * gv.w + bev.w;
    *(float4*)(out + base + c0) = o;
}

extern "C" void kernel_launch(void* const* d_in, const int* in_sizes, int n_in,
                              void* d_out, int out_size, void* d_ws, size_t ws_size,
                              hipStream_t stream) {
    (void)in_sizes; (void)n_in; (void)out_size; (void)ws_size;
    constexpr long S = 2048, E = 1024, F = 4096, M = 8192;

    const float* src = (const float*)d_in[0];
    const float* Wq  = (const float*)d_in[1];
    const float* bq  = (const float*)d_in[2];
    const float* Wk  = (const float*)d_in[3];
    const float* bk  = (const float*)d_in[4];
    const float* Wv  = (const float*)d_in[5];
    const float* bv  = (const float*)d_in[6];
    const float* Wo  = (const float*)d_in[7];
    const float* bo  = (const float*)d_in[8];
    const float* W1  = (const float*)d_in[9];
    const float* b1  = (const float*)d_in[10];
    const float* W2  = (const float*)d_in[11];
    const float* b2  = (const float*)d_in[12];
    const float* g1  = (const float*)d_in[13];
    const float* be1 = (const float*)d_in[14];
    const float* g2  = (const float*)d_in[15];
    const float* be2 = (const float*)d_in[16];

    char* ws = (char*)d_ws;
    size_t off = 0;
    auto take = [&](size_t bytes) {
        char* p = ws + off;
        off += (bytes + 255) & ~(size_t)255;
        return p;
    };
    const size_t MB16 = 16777216;  // f16 [8192][1024]
    u16*   srcH  = (u16*)take(MB16);
    u16*   WqkvT = (u16*)take(3 * E * E * 2);     // [3072][1024]: WqT | WkT | WvT
    u16*   WoT   = (u16*)take(E * E * 2);
    u16*   W1T   = (u16*)take(F * E * 2);         // [4096][1024]
    u16*   W2T   = (u16*)take(E * F * 2);         // [1024][4096]
    char*  B0    = take(2 * MB16);                // QK f16 [8192][2048]
    char*  B1    = take(MB16);                    // VT f16 [4][1024][2048]
    char*  B2    = take(4ull * S * S * 4);        // Sh f16 (32M) -> hf f16 [8192][4096] (64M)
    char*  B3    = take(MB16);                    // attn f16 -> xh f16
    char*  B4    = take(MB16);                    // attnO f16 -> ffO f16

    u16*   QK    = (u16*)B0;
    u16*   VT    = (u16*)B1;
    u16*   Sh    = (u16*)B2;
    u16*   hf    = (u16*)B2;
    u16*   attn  = (u16*)B3;
    u16*   xh    = (u16*)B3;
    u16*   attnO = (u16*)B4;
    u16*   ffO   = (u16*)B4;

    dim3 blk(256), blk5(512), tb(32, 8);

    // 1) convert src -> f16
    cvt_f16<<<dim3(M * E / 8 / 256), blk, 0, stream>>>(src, srcH, M * E / 8);

    // 2) all weight transposes in one launch
    transpose_all<<<dim3(12288), tb, 0, stream>>>(Wq, Wk, Wv, Wo, W1, W2,
                                                  WqkvT, WoT, W1T, W2T);

    // 3) merged Q|K|V projection: 768 blocks
    gemm256n<3, 3, false, 24, 32, 1><<<dim3(24 * 32), blk5, 0, stream>>>(
        srcH, E, 0, WqkvT, E, 0, QK, 2 * E, E * S, VT, bq, bk, bv, E);

    // 4) scores[b] = Q[b] @ K[b]^T: 512 blocks
    gemm256n<0, 0, false, 16, 8, 4><<<dim3(16 * 8 * 4), blk5, 0, stream>>>(
        QK, 2 * E, S * 2 * E, QK + E, 2 * E, S * 2 * E,
        Sh, S, S * S, nullptr, nullptr, nullptr, nullptr, E);

    // 5) softmax in place (f16, vectorized + wave-reduce)
    softmax_rows<<<dim3(M), blk, 0, stream>>>(Sh);

    // 6) attn[b] = P[b] @ V[b]: 256 blocks
    gemm256n<0, 0, false, 8, 8, 4><<<dim3(8 * 8 * 4), blk5, 0, stream>>>(
        Sh, S, S * S, VT, S, E * S,
        attn, E, S * E, nullptr, nullptr, nullptr, nullptr, S);

    // 7) attnO = attn @ Wo + bo: 256 blocks
    gemm256n<0, 1, false, 8, 32, 1><<<dim3(8 * 32), blk5, 0, stream>>>(
        attn, E, 0, WoT, E, 0, attnO, E, 0, nullptr, bo, nullptr, nullptr, E);

    // 8) xh = LN(src + attnO) (f16, over dead attn)
    ln_one<<<dim3(M), blk, 0, stream>>>(src, attnO, g1, be1, xh);

    // 9) hf = relu(xh @ W1 + b1): 1024 blocks (r6-proven config)
    gemm256n<0, 1, true, 32, 32, 1><<<dim3(32 * 32), blk5, 0, stream>>>(
        xh, E, 0, W1T, E, 0, hf, F, 0, nullptr, b1, nullptr, nullptr, E);

    // 10) ffO = hf @ W2 + b2: 256 blocks, K=4096
    gemm256n<0, 1, false, 8, 32, 1><<<dim3(8 * 32), blk5, 0, stream>>>(
        hf, F, 0, W2T, F, 0, ffO, E, 0, nullptr, b2, nullptr, nullptr, F);

    // 11) out = LN(xh + ffO) -> f32
    ln_two<<<dim3(M), blk, 0, stream>>>(xh, ffO, g2, be2, (float*)d_out);
}

// Round 9
// 478.529 us; speedup vs baseline: 1.0751x; 1.0062x over previous
//
#include <hip/hip_runtime.h>
#include <stdint.h>

typedef unsigned short u16;
typedef _Float16 v8h __attribute__((ext_vector_type(8)));
typedef float v4f __attribute__((ext_vector_type(4)));

static __device__ __forceinline__ float h2f(u16 u) {
    union { u16 s; _Float16 h; } v; v.s = u; return (float)v.h;
}
static __device__ __forceinline__ u16 f2h(float f) {
    union { u16 s; _Float16 h; } v; v.h = (_Float16)f; return v.s;
}

// async global->LDS, 16B per lane. lds dest = wave-uniform base + lane*16.
static __device__ __forceinline__ void gload_lds16(const u16* g, const u16* l) {
    __builtin_amdgcn_global_load_lds(
        (const __attribute__((address_space(1))) uint32_t*)(uintptr_t)g,
        (__attribute__((address_space(3))) uint32_t*)(uintptr_t)l,
        16, 0, 0);
}

// ---------------- convert f32 -> f16, vectorized x8 ----------------
__global__ __launch_bounds__(256) void cvt_f16(const float* __restrict__ in,
                                               u16* __restrict__ out, int n8) {
    const int i = blockIdx.x * 256 + threadIdx.x;
    if (i >= n8) return;
    const float4 a = ((const float4*)in)[2 * i];
    const float4 b = ((const float4*)in)[2 * i + 1];
    u16 o[8] = {f2h(a.x), f2h(a.y), f2h(a.z), f2h(a.w),
                f2h(b.x), f2h(b.y), f2h(b.z), f2h(b.w)};
    *(uint4*)(out + (size_t)i * 8) = *(const uint4*)o;
}

// ---------------- all weight transposes f32 [R][C] -> f16 [C][R], one launch ----------------
__global__ __launch_bounds__(256) void transpose_all(
    const float* __restrict__ Wq, const float* __restrict__ Wk,
    const float* __restrict__ Wv, const float* __restrict__ Wo,
    const float* __restrict__ W1, const float* __restrict__ W2,
    u16* __restrict__ WqkvT, u16* __restrict__ WoT,
    u16* __restrict__ W1T, u16* __restrict__ W2T)
{
    int t = blockIdx.x;
    const float* in; u16* out; long ldi, ldo; int xt;
    if (t < 1024)      {            in = Wq; out = WqkvT;               ldi = 1024; ldo = 1024; xt = 32; }
    else if (t < 2048) { t -= 1024; in = Wk; out = WqkvT + 1024*1024;   ldi = 1024; ldo = 1024; xt = 32; }
    else if (t < 3072) { t -= 2048; in = Wv; out = WqkvT + 2*1024*1024; ldi = 1024; ldo = 1024; xt = 32; }
    else if (t < 4096) { t -= 3072; in = Wo; out = WoT;                 ldi = 1024; ldo = 1024; xt = 32; }
    else if (t < 8192) { t -= 4096; in = W1; out = W1T;                 ldi = 4096; ldo = 1024; xt = 128; }
    else               { t -= 8192; in = W2; out = W2T;                 ldi = 1024; ldo = 4096; xt = 32; }
    const int c0 = (t % xt) * 32, r0 = (t / xt) * 32;
    __shared__ float tile[32][33];
    for (int i = threadIdx.y; i < 32; i += 8)
        tile[i][threadIdx.x] = in[(long)(r0 + i) * ldi + c0 + threadIdx.x];
    __syncthreads();
    for (int i = threadIdx.y; i < 32; i += 8)
        out[(long)(c0 + i) * ldo + r0 + threadIdx.x] = f2h(tile[threadIdx.x][i]);
}

// ======== 256x128 8-phase f16 GEMM, 4 waves 2Mx2N (per-wave 128x64) ========
// NEW vs r6: per-wave tile 64x64 -> 128x64. Rationale: LDS-read/MFMA cycle
// ratio = 47.7*(m+n)/(m*n); 64x64 -> 1.49 (serialized util bound 40%, we
// measured 36-37% across ALL schedule variants); 128x64 -> 1.12 (bound 47%).
// 4-wave/256-thr block keeps the SAME 80 KiB LDS layout -> 2 blocks/CU
// (the cross-gang overlap r2's 1-block 128x64 variant lacked).
// Skeleton (regions, slots, phase order, barrier placement) identical to
// the r6-proven kernel; stage calls are 4 KiB (256 lanes x 16B) so counts
// double: prologue 16 loads -> vmcnt(10) leaves A1(4)+B1(2)+A2(4);
// even-phase-top vmcnt(4) leaves the prior odd phase's 4 A-calls (full
// FIFO trace verified: every region's completion-wait precedes its
// cross-wave use by >=2 barriers; WAR on restage protected by per-wave
// lgkmcnt(0)-before-MFMA + trailing barrier). k-order per output element
// unchanged -> bit-identical results.
template<int OMODE, int BIAS, bool RELU, int NX, int NY, int NZ>
__global__ __launch_bounds__(256, 2) void gemm256n(
    const u16* __restrict__ A, long lda, long Asb,
    const u16* __restrict__ B, long ldb, long Bsb,
    void* __restrict__ Cv, long ldc, long Csb, u16* __restrict__ C1,
    const float* __restrict__ bias, const float* __restrict__ bias2,
    const float* __restrict__ bias3, int K)
{
    constexpr int NWG = NX * NY * NZ;
    static_assert(NWG % 8 == 0, "XCD swizzle needs nwg % 8 == 0");
    alignas(16) __shared__ u16 As[4 * 8192];   // 64 KiB: 4 regions [256][32]
    alignas(16) __shared__ u16 Bs[2 * 4096];   // 16 KiB: 2 slots [128][32]

    const int tid = threadIdx.x;               // 0..255
    const int lane = tid & 63, wave = tid >> 6; // wave 0..3
    const int l16 = lane & 15, quad = lane >> 4;
    const int wm = wave >> 1;              // 0..1 (M, 128 rows each)
    const int wn = wave & 1;               // 0..1 (N, 64 cols each)

    const int lin = blockIdx.x;
    const int tl = (lin & 7) * (NWG / 8) + (lin >> 3);
    const int xe = tl % NX;
    const int ye = (tl / NX) % NY;
    const int zb = tl / (NX * NY);
    const long m0 = (long)ye * 256;
    const long n0 = (long)xe * 128;

    const u16* Aop = A + (long)zb * Asb;
    const u16* Bop = B + (long)zb * Bsb;

    const int srow = tid >> 2;                       // 0..63
    const int sq = (tid & 3) ^ ((tid >> 3) & 3);
    const long gaofs0 = (m0 + srow) * lda + sq * 8;  // call p adds p*64*lda
    const long gbofs0 = (n0 + srow) * ldb + sq * 8;  // call p adds p*64*ldb
    const int wv512n = wave * 512;                   // 4 waves x 512 = 2048/call

    const int swzE = (quad ^ ((l16 >> 1) & 3)) * 8;
    const int aRow = (wm * 128 + l16) * 32 + swzE;
    const int bRow = (wn * 64 + l16) * 32 + swzE;

    v4f acc[8][4];
#pragma unroll
    for (int i = 0; i < 8; ++i)
#pragma unroll
        for (int j = 0; j < 4; ++j)
            acc[i][j] = (v4f){0.f, 0.f, 0.f, 0.f};
    v8h bf[4];

#define STAGE_A(RIDX, KP) do { \
        u16* lb_ = As + (RIDX) * 8192 + wv512n; \
        gload_lds16(Aop + gaofs0 + (KP), lb_); \
        gload_lds16(Aop + gaofs0 + 64 * lda + (KP), lb_ + 2048); \
        gload_lds16(Aop + gaofs0 + 128 * lda + (KP), lb_ + 4096); \
        gload_lds16(Aop + gaofs0 + 192 * lda + (KP), lb_ + 6144); } while (0)
#define STAGE_B(SLOT, KP) do { \
        u16* lb_ = Bs + (SLOT) * 4096 + wv512n; \
        gload_lds16(Bop + gbofs0 + (KP), lb_); \
        gload_lds16(Bop + gbofs0 + 64 * ldb + (KP), lb_ + 2048); } while (0)

// Phase (BUF,KH,CH): rows CH*64..CH*64+63 of the wave's 128, K-32 chunk
// (BUF*2+KH). 4 A frags + (CH==0: 4 B frags), 16 MFMA.
#define PHASE(BUF, KH, CH, EVENW, STG) { \
        if (EVENW) asm volatile("s_waitcnt vmcnt(4)" ::: "memory"); \
        const u16* Ar_ = As + ((BUF) * 2 + (KH)) * 8192 + aRow + (CH) * 2048; \
        v8h af0 = *(const v8h*)(Ar_); \
        v8h af1 = *(const v8h*)(Ar_ + 512); \
        v8h af2 = *(const v8h*)(Ar_ + 1024); \
        v8h af3 = *(const v8h*)(Ar_ + 1536); \
        if ((CH) == 0) { \
            const u16* Br_ = Bs + (KH) * 4096 + bRow; \
            bf[0] = *(const v8h*)(Br_); \
            bf[1] = *(const v8h*)(Br_ + 512); \
            bf[2] = *(const v8h*)(Br_ + 1024); \
            bf[3] = *(const v8h*)(Br_ + 1536); \
        } \
        STG; \
        __builtin_amdgcn_s_barrier(); \
        asm volatile("s_waitcnt lgkmcnt(0)" ::: "memory"); \
        __builtin_amdgcn_s_setprio(1); \
        acc[(CH)*4+0][0] = __builtin_amdgcn_mfma_f32_16x16x32_f16(af0, bf[0], acc[(CH)*4+0][0], 0, 0, 0); \
        acc[(CH)*4+0][1] = __builtin_amdgcn_mfma_f32_16x16x32_f16(af0, bf[1], acc[(CH)*4+0][1], 0, 0, 0); \
        acc[(CH)*4+0][2] = __builtin_amdgcn_mfma_f32_16x16x32_f16(af0, bf[2], acc[(CH)*4+0][2], 0, 0, 0); \
        acc[(CH)*4+0][3] = __builtin_amdgcn_mfma_f32_16x16x32_f16(af0, bf[3], acc[(CH)*4+0][3], 0, 0, 0); \
        acc[(CH)*4+1][0] = __builtin_amdgcn_mfma_f32_16x16x32_f16(af1, bf[0], acc[(CH)*4+1][0], 0, 0, 0); \
        acc[(CH)*4+1][1] = __builtin_amdgcn_mfma_f32_16x16x32_f16(af1, bf[1], acc[(CH)*4+1][1], 0, 0, 0); \
        acc[(CH)*4+1][2] = __builtin_amdgcn_mfma_f32_16x16x32_f16(af1, bf[2], acc[(CH)*4+1][2], 0, 0, 0); \
        acc[(CH)*4+1][3] = __builtin_amdgcn_mfma_f32_16x16x32_f16(af1, bf[3], acc[(CH)*4+1][3], 0, 0, 0); \
        acc[(CH)*4+2][0] = __builtin_amdgcn_mfma_f32_16x16x32_f16(af2, bf[0], acc[(CH)*4+2][0], 0, 0, 0); \
        acc[(CH)*4+2][1] = __builtin_amdgcn_mfma_f32_16x16x32_f16(af2, bf[1], acc[(CH)*4+2][1], 0, 0, 0); \
        acc[(CH)*4+2][2] = __builtin_amdgcn_mfma_f32_16x16x32_f16(af2, bf[2], acc[(CH)*4+2][2], 0, 0, 0); \
        acc[(CH)*4+2][3] = __builtin_amdgcn_mfma_f32_16x16x32_f16(af2, bf[3], acc[(CH)*4+2][3], 0, 0, 0); \
        acc[(CH)*4+3][0] = __builtin_amdgcn_mfma_f32_16x16x32_f16(af3, bf[0], acc[(CH)*4+3][0], 0, 0, 0); \
        acc[(CH)*4+3][1] = __builtin_amdgcn_mfma_f32_16x16x32_f16(af3, bf[1], acc[(CH)*4+3][1], 0, 0, 0); \
        acc[(CH)*4+3][2] = __builtin_amdgcn_mfma_f32_16x16x32_f16(af3, bf[2], acc[(CH)*4+3][2], 0, 0, 0); \
        acc[(CH)*4+3][3] = __builtin_amdgcn_mfma_f32_16x16x32_f16(af3, bf[3], acc[(CH)*4+3][3], 0, 0, 0); \
        __builtin_amdgcn_s_setprio(0); \
        __builtin_amdgcn_s_barrier(); \
    }

    // prologue: A r0,r1,r2 + B s0,s1 (16 loads); vmcnt(10) leaves A1,B1,A2
    STAGE_A(0, 0);  STAGE_B(0, 0);
    STAGE_A(1, 32); STAGE_B(1, 32);
    STAGE_A(2, 64);
    asm volatile("s_waitcnt vmcnt(10)" ::: "memory");
    __builtin_amdgcn_s_barrier();

    const int NT = K >> 7;   // K % 128 == 0
#pragma unroll 1
    for (int t = 0; t < NT; ++t) {
        const long kb = (long)t * 128;
        long kp2  = kb + 128; if (kp2  >= K) kp2  = 0;
        long kp2b = kb + 160; if (kp2b >= K) kp2b = 0;
        long kp3  = kb + 192; if (kp3  >= K) kp3  = 0;

        PHASE(0, 0, 0, false, STAGE_A(3, kb + 96))   // P1
        PHASE(0, 0, 1, true,  STAGE_B(0, kb + 64))   // P2
        PHASE(0, 1, 0, false, STAGE_A(0, kp2))       // P3
        PHASE(0, 1, 1, true,  STAGE_B(1, kb + 96))   // P4
        PHASE(1, 0, 0, false, STAGE_A(1, kp2b))      // P5
        PHASE(1, 0, 1, true,  STAGE_B(0, kp2))       // P6
        PHASE(1, 1, 0, false, STAGE_A(2, kp3))       // P7
        PHASE(1, 1, 1, true,  STAGE_B(1, kp2b))      // P8
    }

    // hardened: drain all outstanding DMA/LDS ops before epilogue/endpgm
    asm volatile("s_waitcnt vmcnt(0) lgkmcnt(0)" ::: "memory");
    __builtin_amdgcn_s_barrier();

#undef PHASE
#undef STAGE_A
#undef STAGE_B

    float bv[4];
#pragma unroll
    for (int j = 0; j < 4; ++j) {
        const long col = n0 + wn * 64 + j * 16 + l16;
        if (BIAS == 0) bv[j] = 0.f;
        else if (BIAS == 1) bv[j] = bias[col];
        else {
            const int sel = (int)(col >> 10);
            const float* bp = sel == 0 ? bias : (sel == 1 ? bias2 : bias3);
            bv[j] = bp[col & 1023];
        }
    }

    if (OMODE == 3 && n0 >= 2048) {
        const long bb = m0 >> 11, mb = m0 & 2047;
        u16* C = C1 + bb * Csb;
#pragma unroll
        for (int j = 0; j < 4; ++j) {
            const long col = n0 - 2048 + wn * 64 + j * 16 + l16;
            u16* pc = C + col * 2048 + mb + wm * 128 + quad * 4;
#pragma unroll
            for (int i = 0; i < 8; ++i) {
                u16 o[4];
#pragma unroll
                for (int r = 0; r < 4; ++r) {
                    float val = acc[i][j][r] + bv[j];
                    if (RELU) val = fmaxf(val, 0.f);
                    o[r] = f2h(val);
                }
                *(uint2*)(pc + i * 16) = *(const uint2*)o;
            }
        }
    } else {
        const long cb = (OMODE == 3 ? 0 : (long)zb * Csb)
                      + (m0 + wm * 128 + quad * 4) * ldc + (n0 + wn * 64 + l16);
        u16* p0 = (u16*)Cv + cb;
#pragma unroll
        for (int i = 0; i < 8; ++i)
#pragma unroll
            for (int r = 0; r < 4; ++r) {
                u16* prow = p0 + (long)(i * 16 + r) * ldc;
#pragma unroll
                for (int j = 0; j < 4; ++j) {
                    float val = acc[i][j][r] + bv[j];
                    if (RELU) val = fmaxf(val, 0.f);
                    prow[j * 16] = f2h(val);
                }
            }
    }
}

// ---------------- softmax over f16 rows of 2048, in place ----------------
// Vectorized (uint4 = 8 f16 contiguous per thread) + wave shuffle reduce.
__global__ __launch_bounds__(256) void softmax_rows(u16* __restrict__ S) {
    const long row = blockIdx.x;
    u16* p = S + row * 2048;
    const int t = threadIdx.x;
    const int lane = t & 63, wv = t >> 6;

    union { uint4 u; u16 h[8]; } ld;
    ld.u = *(const uint4*)(p + t * 8);
    float v[8];
    float mx = -1e30f;
#pragma unroll
    for (int i = 0; i < 8; ++i) { v[i] = h2f(ld.h[i]); mx = fmaxf(mx, v[i]); }
#pragma unroll
    for (int o = 1; o < 64; o <<= 1) mx = fmaxf(mx, __shfl_xor(mx, o, 64));
    __shared__ float cw[4], cs[4];
    if (lane == 0) cw[wv] = mx;
    __syncthreads();
    mx = fmaxf(fmaxf(cw[0], cw[1]), fmaxf(cw[2], cw[3]));

    float sum = 0.f;
#pragma unroll
    for (int i = 0; i < 8; ++i) { v[i] = __expf(v[i] - mx); sum += v[i]; }
#pragma unroll
    for (int o = 1; o < 64; o <<= 1) sum += __shfl_xor(sum, o, 64);
    if (lane == 0) cs[wv] = sum;
    __syncthreads();
    sum = (cs[0] + cs[1]) + (cs[2] + cs[3]);

    const float inv = 1.f / sum;
#pragma unroll
    for (int i = 0; i < 8; ++i) ld.h[i] = f2h(v[i] * inv);
    *(uint4*)(p + t * 8) = ld.u;
}

// ---------------- ln1: xh_f16 = LN(src_f32 + attnO_f16) ----------------
__global__ __launch_bounds__(256) void ln_one(
    const float* __restrict__ a, const u16* __restrict__ bb,
    const float* __restrict__ g, const float* __restrict__ be,
    u16* __restrict__ out16)
{
    const long base = (long)blockIdx.x * 1024;
    const int t = threadIdx.x;
    const int lane = t & 63, wv = t >> 6;
    const int c0 = t * 4;

    const float4 av = *(const float4*)(a + base + c0);
    union { uint2 u; u16 h[4]; } bv;
    bv.u = *(const uint2*)(bb + base + c0);
    float v[4] = {av.x + h2f(bv.h[0]), av.y + h2f(bv.h[1]),
                  av.z + h2f(bv.h[2]), av.w + h2f(bv.h[3])};
    float s = 0.f, ss = 0.f;
#pragma unroll
    for (int i = 0; i < 4; ++i) { s += v[i]; ss += v[i] * v[i]; }
#pragma unroll
    for (int o = 1; o < 64; o <<= 1) { s += __shfl_xor(s, o, 64); ss += __shfl_xor(ss, o, 64); }
    __shared__ float cs[4], css[4];
    if (lane == 0) { cs[wv] = s; css[wv] = ss; }
    __syncthreads();
    s  = (cs[0] + cs[1]) + (cs[2] + cs[3]);
    ss = (css[0] + css[1]) + (css[2] + css[3]);

    const float mean = s * (1.f / 1024.f);
    const float var = ss * (1.f / 1024.f) - mean * mean;
    const float rstd = rsqrtf(var + 1e-5f);
    const float4 gv = *(const float4*)(g + c0);
    const float4 bev = *(const float4*)(be + c0);
    u16 o[4] = {f2h((v[0] - mean) * rstd * gv.x + bev.x),
                f2h((v[1] - mean) * rstd * gv.y + bev.y),
                f2h((v[2] - mean) * rstd * gv.z + bev.z),
                f2h((v[3] - mean) * rstd * gv.w + bev.w)};
    *(uint2*)(out16 + base + c0) = *(const uint2*)o;
}

// ---------------- ln2: out_f32 = LN(xh_f16 + ffO_f16) ----------------
__global__ __launch_bounds__(256) void ln_two(
    const u16* __restrict__ a, const u16* __restrict__ bb,
    const float* __restrict__ g, const float* __restrict__ be,
    float* __restrict__ out)
{
    const long base = (long)blockIdx.x * 1024;
    const int t = threadIdx.x;
    const int lane = t & 63, wv = t >> 6;
    const int c0 = t * 4;

    union { uint2 u; u16 h[4]; } avu, bvu;
    avu.u = *(const uint2*)(a + base + c0);
    bvu.u = *(const uint2*)(bb + base + c0);
    float v[4];
    float s = 0.f, ss = 0.f;
#pragma unroll
    for (int i = 0; i < 4; ++i) {
        v[i] = h2f(avu.h[i]) + h2f(bvu.h[i]);
        s += v[i]; ss += v[i] * v[i];
    }
#pragma unroll
    for (int o = 1; o < 64; o <<= 1) { s += __shfl_xor(s, o, 64); ss += __shfl_xor(ss, o, 64); }
    __shared__ float cs[4], css[4];
    if (lane == 0) { cs[wv] = s; css[wv] = ss; }
    __syncthreads();
    s  = (cs[0] + cs[1]) + (cs[2] + cs[3]);
    ss = (css[0] + css[1]) + (css[2] + css[3]);

    const float mean = s * (1.f / 1024.f);
    const float var = ss * (1.f / 1024.f) - mean * mean;
    const float rstd = rsqrtf(var + 1e-5f);
    const float4 gv = *(const float4*)(g + c0);
    const float4 bev = *(const float4*)(be + c0);
    float4 o;
    o.x = (v[0] - mean) * rstd * gv.x + bev.x;
    o.y = (v[1] - mean) * rstd * gv.y + bev.y;
    o.z = (v[2] - mean) * rstd * gv.z + bev.z;
    o.w = (v[3] - mean) * rstd * gv.w + bev.w;
    *(float4*)(out + base + c0) = o;
}

extern "C" void kernel_launch(void* const* d_in, const int* in_sizes, int n_in,
                              void* d_out, int out_size, void* d_ws, size_t ws_size,
                              hipStream_t stream) {
    (void)in_sizes; (void)n_in; (void)out_size; (void)ws_size;
    constexpr long S = 2048, E = 1024, F = 4096, M = 8192;

    const float* src = (const float*)d_in[0];
    const float* Wq  = (const float*)d_in[1];
    const float* bq  = (const float*)d_in[2];
    const float* Wk  = (const float*)d_in[3];
    const float* bk  = (const float*)d_in[4];
    const float* Wv  = (const float*)d_in[5];
    const float* bv  = (const float*)d_in[6];
    const float* Wo  = (const float*)d_in[7];
    const float* bo  = (const float*)d_in[8];
    const float* W1  = (const float*)d_in[9];
    const float* b1  = (const float*)d_in[10];
    const float* W2  = (const float*)d_in[11];
    const float* b2  = (const float*)d_in[12];
    const float* g1  = (const float*)d_in[13];
    const float* be1 = (const float*)d_in[14];
    const float* g2  = (const float*)d_in[15];
    const float* be2 = (const float*)d_in[16];

    char* ws = (char*)d_ws;
    size_t off = 0;
    auto take = [&](size_t bytes) {
        char* p = ws + off;
        off += (bytes + 255) & ~(size_t)255;
        return p;
    };
    const size_t MB16 = 16777216;  // f16 [8192][1024]
    u16*   srcH  = (u16*)take(MB16);
    u16*   WqkvT = (u16*)take(3 * E * E * 2);     // [3072][1024]: WqT | WkT | WvT
    u16*   WoT   = (u16*)take(E * E * 2);
    u16*   W1T   = (u16*)take(F * E * 2);         // [4096][1024]
    u16*   W2T   = (u16*)take(E * F * 2);         // [1024][4096]
    char*  B0    = take(2 * MB16);                // QK f16 [8192][2048]
    char*  B1    = take(MB16);                    // VT f16 [4][1024][2048]
    char*  B2    = take(4ull * S * S * 4);        // Sh f16 (32M) -> hf f16 [8192][4096] (64M)
    char*  B3    = take(MB16);                    // attn f16 -> xh f16
    char*  B4    = take(MB16);                    // attnO f16 -> ffO f16

    u16*   QK    = (u16*)B0;
    u16*   VT    = (u16*)B1;
    u16*   Sh    = (u16*)B2;
    u16*   hf    = (u16*)B2;
    u16*   attn  = (u16*)B3;
    u16*   xh    = (u16*)B3;
    u16*   attnO = (u16*)B4;
    u16*   ffO   = (u16*)B4;

    dim3 blk(256), tb(32, 8);

    // 1) convert src -> f16
    cvt_f16<<<dim3(M * E / 8 / 256), blk, 0, stream>>>(src, srcH, M * E / 8);

    // 2) all weight transposes in one launch
    transpose_all<<<dim3(12288), tb, 0, stream>>>(Wq, Wk, Wv, Wo, W1, W2,
                                                  WqkvT, WoT, W1T, W2T);

    // 3) merged Q|K|V projection: 768 blocks
    gemm256n<3, 3, false, 24, 32, 1><<<dim3(24 * 32), blk, 0, stream>>>(
        srcH, E, 0, WqkvT, E, 0, QK, 2 * E, E * S, VT, bq, bk, bv, E);

    // 4) scores[b] = Q[b] @ K[b]^T: 512 blocks
    gemm256n<0, 0, false, 16, 8, 4><<<dim3(16 * 8 * 4), blk, 0, stream>>>(
        QK, 2 * E, S * 2 * E, QK + E, 2 * E, S * 2 * E,
        Sh, S, S * S, nullptr, nullptr, nullptr, nullptr, E);

    // 5) softmax in place (f16, vectorized + wave-reduce)
    softmax_rows<<<dim3(M), blk, 0, stream>>>(Sh);

    // 6) attn[b] = P[b] @ V[b]: 256 blocks
    gemm256n<0, 0, false, 8, 8, 4><<<dim3(8 * 8 * 4), blk, 0, stream>>>(
        Sh, S, S * S, VT, S, E * S,
        attn, E, S * E, nullptr, nullptr, nullptr, nullptr, S);

    // 7) attnO = attn @ Wo + bo: 256 blocks
    gemm256n<0, 1, false, 8, 32, 1><<<dim3(8 * 32), blk, 0, stream>>>(
        attn, E, 0, WoT, E, 0, attnO, E, 0, nullptr, bo, nullptr, nullptr, E);

    // 8) xh = LN(src + attnO) (f16, over dead attn)
    ln_one<<<dim3(M), blk, 0, stream>>>(src, attnO, g1, be1, xh);

    // 9) hf = relu(xh @ W1 + b1): 1024 blocks
    gemm256n<0, 1, true, 32, 32, 1><<<dim3(32 * 32), blk, 0, stream>>>(
        xh, E, 0, W1T, E, 0, hf, F, 0, nullptr, b1, nullptr, nullptr, E);

    // 10) ffO = hf @ W2 + b2: 256 blocks, K=4096
    gemm256n<0, 1, false, 8, 32, 1><<<dim3(8 * 32), blk, 0, stream>>>(
        hf, F, 0, W2T, F, 0, ffO, E, 0, nullptr, b2, nullptr, nullptr, F);

    // 11) out = LN(xh + ffO) -> f32
    ln_two<<<dim3(M), blk, 0, stream>>>(xh, ffO, g2, be2, (float*)d_out);
}